// Round 1
// baseline (621.098 us; speedup 1.0000x reference)
//
#include <hip/hip_runtime.h>
#include <math.h>

#define NB 8
#define NL 1024
#define ND 512
#define NF 513          // rfft bins of length-1024 transform
#define NT 2047         // L + S - 1
#define TOPK 20         // int(3 * log(1024))
#define ROWS_PER_BLOCK 8

static __device__ __forceinline__ void rot(float& c, float& s, float cf, float sf) {
    float nc = c * cf - s * sf;
    float ns = s * cf + c * sf;
    c = nc; s = ns;
}

// ---------------------------------------------------------------------------
// Kernel A: per-(b,l) row, compute Q[f],K[f] (rfft of 512-pt real signal zero-
// padded to 1024) for f=0..512, accumulate P̄[b,f] = Σ_l Q·conj(K) into ws.
// Each thread owns bins f=t and f=t+256; bin 512 (Nyquist, real) via reduce.
// ---------------------------------------------------------------------------
__global__ __launch_bounds__(256) void k_spec(const float* __restrict__ q,
                                              const float* __restrict__ kk,
                                              float* __restrict__ pbar) {
    __shared__ float qrow[ND];
    __shared__ float krow[ND];
    __shared__ float red[8];
    const int b  = blockIdx.y;
    const int l0 = blockIdx.x * ROWS_PER_BLOCK;
    const int t  = threadIdx.x;
    const int f0 = t, f1 = t + 256;
    const float w = -2.0f * 3.14159265358979323846f / 1024.0f;
    float cf0, sf0, cf1, sf1;
    sincosf(w * (float)f0, &sf0, &cf0);
    sincosf(w * (float)f1, &sf1, &cf1);
    float P0re = 0.f, P0im = 0.f, P1re = 0.f, P1im = 0.f, P512 = 0.f;

    for (int r = 0; r < ROWS_PER_BLOCK; ++r) {
        const int l = l0 + r;
        const float2* qp = (const float2*)(q  + ((size_t)b * NL + l) * ND);
        const float2* kp = (const float2*)(kk + ((size_t)b * NL + l) * ND);
        __syncthreads();                      // protect LDS reuse
        ((float2*)qrow)[t] = qp[t];
        ((float2*)krow)[t] = kp[t];
        __syncthreads();

        float Q0re = 0.f, Q0im = 0.f, K0re = 0.f, K0im = 0.f;
        float Q1re = 0.f, Q1im = 0.f, K1re = 0.f, K1im = 0.f;
        float c0 = 1.f, s0 = 0.f, c1 = 1.f, s1 = 0.f;
        #pragma unroll 4
        for (int d = 0; d < ND; ++d) {
            if ((d & 63) == 0 && d != 0) {    // kill rotation drift
                sincosf(w * (float)((f0 * d) & 1023), &s0, &c0);
                sincosf(w * (float)((f1 * d) & 1023), &s1, &c1);
            }
            const float qv = qrow[d];         // LDS broadcast (conflict-free)
            const float kv = krow[d];
            Q0re = fmaf(qv, c0, Q0re); Q0im = fmaf(qv, s0, Q0im);
            K0re = fmaf(kv, c0, K0re); K0im = fmaf(kv, s0, K0im);
            Q1re = fmaf(qv, c1, Q1re); Q1im = fmaf(qv, s1, Q1im);
            K1re = fmaf(kv, c1, K1re); K1im = fmaf(kv, s1, K1im);
            rot(c0, s0, cf0, sf0);
            rot(c1, s1, cf1, sf1);
        }
        // P += Q * conj(K)
        P0re += Q0re * K0re + Q0im * K0im;
        P0im += Q0im * K0re - Q0re * K0im;
        P1re += Q1re * K1re + Q1im * K1im;
        P1im += Q1im * K1re - Q1re * K1im;

        // bin 512: Q[512] = Σ (-1)^d q[d]  (real)
        float dq = qrow[2 * t] - qrow[2 * t + 1];
        float dk = krow[2 * t] - krow[2 * t + 1];
        #pragma unroll
        for (int off = 32; off; off >>= 1) {
            dq += __shfl_down(dq, off);
            dk += __shfl_down(dk, off);
        }
        const int wid = t >> 6;
        if ((t & 63) == 0) { red[wid * 2] = dq; red[wid * 2 + 1] = dk; }
        __syncthreads();
        if (t == 0) {
            float Q512 = red[0] + red[2] + red[4] + red[6];
            float K512 = red[1] + red[3] + red[5] + red[7];
            P512 += Q512 * K512;
        }
    }
    float* pb = pbar + (size_t)b * (2 * NF);
    atomicAdd(&pb[2 * f0],     P0re);
    atomicAdd(&pb[2 * f0 + 1], P0im);
    atomicAdd(&pb[2 * f1],     P1re);
    atomicAdd(&pb[2 * f1 + 1], P1im);
    if (t == 0) atomicAdd(&pb[2 * 512], P512);   // imag stays 0 (memset)
}

// ---------------------------------------------------------------------------
// Kernel B: mean_value[b,t] = (1/(2047*1024)) * (P̄[0] + 2Σ_{f=1..512}
//            (P̄re[f] cos(2πft/2047) - P̄im[f] sin(2πft/2047)))
// ---------------------------------------------------------------------------
__global__ __launch_bounds__(256) void k_mean(const float* __restrict__ pbar,
                                              float* __restrict__ mv) {
    __shared__ float P[2 * NF];
    const int b  = blockIdx.y;
    const int tt = blockIdx.x * 256 + threadIdx.x;
    for (int i = threadIdx.x; i < 2 * NF; i += 256)
        P[i] = pbar[(size_t)b * (2 * NF) + i];
    __syncthreads();
    if (tt >= NT) return;
    const float w = 2.0f * 3.14159265358979323846f / 2047.0f;
    float cf, sf;
    sincosf(w * (float)tt, &sf, &cf);
    float c = cf, s = sf;                 // f=1 twiddle
    float acc = P[0];
    for (int f = 1; f <= 512; ++f) {
        if ((f & 63) == 0) {
            int j = (f * tt) % 2047;
            sincosf(w * (float)j, &s, &c);
        }
        acc += 2.0f * fmaf(P[2 * f], c, -(P[2 * f + 1] * s));
        rot(c, s, cf, sf);
    }
    mv[(size_t)b * NT + tt] = acc * (1.0f / (2047.0f * 1024.0f));
}

// ---------------------------------------------------------------------------
// Kernel C: per-batch exact top-20 (descending, ties -> lower index, matching
// jax.lax.top_k), softmax of values; batch 0's indices become global shifts.
// ---------------------------------------------------------------------------
__global__ __launch_bounds__(64) void k_topk(const float* __restrict__ mv,
                                             float* __restrict__ wts,
                                             int* __restrict__ shifts) {
    __shared__ float v[NT];
    __shared__ float topv[TOPK];
    __shared__ int   topi[TOPK];
    const int b = blockIdx.x;
    const int t = threadIdx.x;
    for (int i = t; i < NT; i += 64) v[i] = mv[(size_t)b * NT + i];
    __syncthreads();
    for (int kkk = 0; kkk < TOPK; ++kkk) {
        float bv = -INFINITY; int bi = 0x7fffffff;
        for (int i = t; i < NT; i += 64) {
            float x = v[i];
            if (x > bv) { bv = x; bi = i; }
        }
        #pragma unroll
        for (int off = 32; off; off >>= 1) {
            float ov = __shfl_down(bv, off);
            int   oi = __shfl_down(bi, off);
            if (ov > bv || (ov == bv && oi < bi)) { bv = ov; bi = oi; }
        }
        bv = __shfl(bv, 0); bi = __shfl(bi, 0);
        if (t == 0) { topv[kkk] = bv; topi[kkk] = bi; }
        v[bi] = -INFINITY;               // all lanes write same value
        __syncthreads();
    }
    if (t == 0) {
        float m = topv[0], sum = 0.f, e[TOPK];
        #pragma unroll
        for (int i = 0; i < TOPK; ++i) { e[i] = expf(topv[i] - m); sum += e[i]; }
        #pragma unroll
        for (int i = 0; i < TOPK; ++i) wts[b * TOPK + i] = e[i] / sum;
        if (b == 0) {
            #pragma unroll
            for (int i = 0; i < TOPK; ++i) shifts[i] = topi[i];
        }
    }
}

// ---------------------------------------------------------------------------
// Kernel D: out[b,l,:] = Σ_k w[b,k] * values[b, (l+shift_k) & 1023, :]
// ---------------------------------------------------------------------------
__global__ __launch_bounds__(128) void k_out(const float* __restrict__ vals,
                                             const float* __restrict__ wts,
                                             const int* __restrict__ shifts,
                                             float* __restrict__ out) {
    __shared__ float w[TOPK];
    __shared__ int   sh[TOPK];
    const int b = blockIdx.y;
    const int l = blockIdx.x;
    const int t = threadIdx.x;
    if (t < TOPK) { w[t] = wts[b * TOPK + t]; sh[t] = shifts[t]; }
    __syncthreads();
    float4 acc = make_float4(0.f, 0.f, 0.f, 0.f);
    const float4* vb = (const float4*)(vals + (size_t)b * NL * ND);
    #pragma unroll 4
    for (int kkk = 0; kkk < TOPK; ++kkk) {
        const int sl = (l + sh[kkk]) & (NL - 1);
        const float4 x = vb[(size_t)sl * (ND / 4) + t];
        const float wk = w[kkk];
        acc.x = fmaf(wk, x.x, acc.x);
        acc.y = fmaf(wk, x.y, acc.y);
        acc.z = fmaf(wk, x.z, acc.z);
        acc.w = fmaf(wk, x.w, acc.w);
    }
    ((float4*)out)[((size_t)b * NL + l) * (ND / 4) + t] = acc;
}

extern "C" void kernel_launch(void* const* d_in, const int* in_sizes, int n_in,
                              void* d_out, int out_size, void* d_ws, size_t ws_size,
                              hipStream_t stream) {
    const float* q = (const float*)d_in[0];
    const float* k = (const float*)d_in[1];
    const float* v = (const float*)d_in[2];
    float* out    = (float*)d_out;
    float* pbar   = (float*)d_ws;            // NB * 2*NF floats (zeroed below)
    float* mv     = pbar + NB * 2 * NF;      // NB * NT floats
    float* wts    = mv + NB * NT;            // NB * TOPK floats
    int*   shifts = (int*)(wts + NB * TOPK); // TOPK ints

    hipMemsetAsync(pbar, 0, NB * 2 * NF * sizeof(float), stream);
    k_spec<<<dim3(NL / ROWS_PER_BLOCK, NB), 256, 0, stream>>>(q, k, pbar);
    k_mean<<<dim3((NT + 255) / 256, NB), 256, 0, stream>>>(pbar, mv);
    k_topk<<<NB, 64, 0, stream>>>(mv, wts, shifts);
    k_out<<<dim3(NL, NB), 128, 0, stream>>>(v, wts, shifts, out);
}

// Round 2
// 331.368 us; speedup vs baseline: 1.8743x; 1.8743x over previous
//
#include <hip/hip_runtime.h>
#include <math.h>

#define NB 8
#define NL 1024
#define ND 512
#define NF 513          // rfft bins of length-1024 transform
#define NT 2047         // L + S - 1
#define TOPK 20         // int(3 * log(1024))

static __device__ __forceinline__ void rot(float& c, float& s, float cf, float sf) {
    float nc = c * cf - s * sf;
    float ns = s * cf + c * sf;
    c = nc; s = ns;
}

// ---------------------------------------------------------------------------
// Kernel G: Gram GEMM  G[b][d][e] = sum_l q[b][l][d] * k[b][l][e]
// with fused diagonal-sum epilogue:  S[b][(d-e)+511] += G[b][d][e].
// Tile 128x128, 256 threads, 8x8 micro-tile (split halves), BK=32, split-K=4.
// ---------------------------------------------------------------------------
#define BM 128
#define BN 128
#define BKG 32
#define KSPLIT 4

__global__ __launch_bounds__(256) void k_gram(const float* __restrict__ q,
                                              const float* __restrict__ kk,
                                              float* __restrict__ S) {
    __shared__ float At[BKG][BM + 4];
    __shared__ float Bt[BKG][BN + 4];
    __shared__ float sd[255];
    const int b  = blockIdx.z;
    const int dt = blockIdx.x >> 2;      // d-tile 0..3
    const int ks = blockIdx.x & 3;       // k-split 0..3
    const int et = blockIdx.y;           // e-tile 0..3
    const int d0 = dt * BM, e0 = et * BN;
    const int tid = threadIdx.x;
    const int ti = tid >> 4;             // 0..15
    const int tj = tid & 15;             // 0..15
    const float* qb = q  + (size_t)b * NL * ND;
    const float* kb = kk + (size_t)b * NL * ND;

    const int lrow = tid >> 3;           // 0..31
    const int lc4  = tid & 7;            // 0..7

    float acc[8][8];
    #pragma unroll
    for (int i = 0; i < 8; ++i)
        #pragma unroll
        for (int j = 0; j < 8; ++j) acc[i][j] = 0.f;

    const int NITER = (NL / KSPLIT) / BKG;   // 8
    const int l0 = ks * (NL / KSPLIT);

    float4 pq[4], pk[4];
    #pragma unroll
    for (int p = 0; p < 4; ++p) {
        pq[p] = *(const float4*)&qb[(size_t)(l0 + lrow) * ND + d0 + (lc4 + 8 * p) * 4];
        pk[p] = *(const float4*)&kb[(size_t)(l0 + lrow) * ND + e0 + (lc4 + 8 * p) * 4];
    }

    for (int it = 0; it < NITER; ++it) {
        __syncthreads();
        #pragma unroll
        for (int p = 0; p < 4; ++p) {
            *(float4*)&At[lrow][(lc4 + 8 * p) * 4] = pq[p];
            *(float4*)&Bt[lrow][(lc4 + 8 * p) * 4] = pk[p];
        }
        __syncthreads();
        if (it + 1 < NITER) {
            const int l1 = l0 + (it + 1) * BKG;
            #pragma unroll
            for (int p = 0; p < 4; ++p) {
                pq[p] = *(const float4*)&qb[(size_t)(l1 + lrow) * ND + d0 + (lc4 + 8 * p) * 4];
                pk[p] = *(const float4*)&kb[(size_t)(l1 + lrow) * ND + e0 + (lc4 + 8 * p) * 4];
            }
        }
        #pragma unroll
        for (int c = 0; c < BKG; ++c) {
            const float4 a0 = *(const float4*)&At[c][ti * 4];
            const float4 a1 = *(const float4*)&At[c][64 + ti * 4];
            const float4 b0 = *(const float4*)&Bt[c][tj * 4];
            const float4 b1 = *(const float4*)&Bt[c][64 + tj * 4];
            const float av[8] = {a0.x, a0.y, a0.z, a0.w, a1.x, a1.y, a1.z, a1.w};
            const float bv[8] = {b0.x, b0.y, b0.z, b0.w, b1.x, b1.y, b1.z, b1.w};
            #pragma unroll
            for (int i = 0; i < 8; ++i)
                #pragma unroll
                for (int j = 0; j < 8; ++j)
                    acc[i][j] = fmaf(av[i], bv[j], acc[i][j]);
        }
    }

    // --- epilogue: reduce acc to diagonal sums ---
    for (int i = tid; i < 255; i += 256) sd[i] = 0.f;
    __syncthreads();
    // per-thread pre-reduction into 21 bins: delta = 4*(ti-tj) + (i'-j') + 64*qd
    float bin[3][7];
    #pragma unroll
    for (int s = 0; s < 3; ++s)
        #pragma unroll
        for (int u = 0; u < 7; ++u) bin[s][u] = 0.f;
    #pragma unroll
    for (int i = 0; i < 8; ++i)
        #pragma unroll
        for (int j = 0; j < 8; ++j)
            bin[(i >> 2) - (j >> 2) + 1][(i & 3) - (j & 3) + 3] += acc[i][j];
    #pragma unroll
    for (int s = 0; s < 3; ++s)
        #pragma unroll
        for (int u = 0; u < 7; ++u) {
            const int dl = 4 * (ti - tj) + (u - 3) + 64 * (s - 1);  // [-127,127]
            atomicAdd(&sd[dl + 127], bin[s][u]);
        }
    __syncthreads();
    const int doff = d0 - e0;
    for (int i = tid; i < 255; i += 256) {
        const int dg = doff + (i - 127);          // [-511,511]
        atomicAdd(&S[b * 1023 + dg + 511], sd[i]);
    }
}

// ---------------------------------------------------------------------------
// Kernel P: P̄[b][f] = sum_j S[b][j] * e^{-2πi f (j-511)/1024}, f = 0..512
// ---------------------------------------------------------------------------
__global__ __launch_bounds__(256) void k_pdft(const float* __restrict__ S,
                                              float* __restrict__ pbar) {
    __shared__ float sh[1023];
    const int b = blockIdx.y;
    const int f = blockIdx.x * 256 + threadIdx.x;
    for (int i = threadIdx.x; i < 1023; i += 256) sh[i] = S[b * 1023 + i];
    __syncthreads();
    if (f > 512) return;
    const float w = 2.0f * 3.14159265358979323846f / 1024.0f;
    float cf, sf;
    sincosf(w * (float)f, &sf, &cf);
    float c = 1.f, s = 0.f;
    float re = 0.f, im = 0.f;
    for (int j = 0; j < 1023; ++j) {
        if ((j & 63) == 0) {                      // reseed (kills drift)
            const int m = (int)(((long long)f * (long long)(j - 511)) & 1023);
            sincosf(w * (float)m, &s, &c);
        }
        const float x = sh[j];
        re = fmaf(x, c, re);
        im = fmaf(x, -s, im);
        rot(c, s, cf, sf);
    }
    pbar[b * 2 * NF + 2 * f]     = re;
    pbar[b * 2 * NF + 2 * f + 1] = im;
}

// ---------------------------------------------------------------------------
// Kernel B: mean_value[b,t] = (1/(2047*1024)) * (P̄[0] + 2Σ_{f=1..512}
//            (P̄re[f] cos(2πft/2047) - P̄im[f] sin(2πft/2047)))
// ---------------------------------------------------------------------------
__global__ __launch_bounds__(256) void k_mean(const float* __restrict__ pbar,
                                              float* __restrict__ mv) {
    __shared__ float P[2 * NF];
    const int b  = blockIdx.y;
    const int tt = blockIdx.x * 256 + threadIdx.x;
    for (int i = threadIdx.x; i < 2 * NF; i += 256)
        P[i] = pbar[(size_t)b * (2 * NF) + i];
    __syncthreads();
    if (tt >= NT) return;
    const float w = 2.0f * 3.14159265358979323846f / 2047.0f;
    float cf, sf;
    sincosf(w * (float)tt, &sf, &cf);
    float c = cf, s = sf;                 // f=1 twiddle
    float acc = P[0];
    for (int f = 1; f <= 512; ++f) {
        if ((f & 63) == 0) {
            int j = (f * tt) % 2047;
            sincosf(w * (float)j, &s, &c);
        }
        acc += 2.0f * fmaf(P[2 * f], c, -(P[2 * f + 1] * s));
        rot(c, s, cf, sf);
    }
    mv[(size_t)b * NT + tt] = acc * (1.0f / (2047.0f * 1024.0f));
}

// ---------------------------------------------------------------------------
// Kernel C: per-batch exact top-20 (descending, ties -> lower index), softmax;
// batch 0's indices become global shifts.
// ---------------------------------------------------------------------------
__global__ __launch_bounds__(64) void k_topk(const float* __restrict__ mv,
                                             float* __restrict__ wts,
                                             int* __restrict__ shifts) {
    __shared__ float v[NT];
    __shared__ float topv[TOPK];
    __shared__ int   topi[TOPK];
    const int b = blockIdx.x;
    const int t = threadIdx.x;
    for (int i = t; i < NT; i += 64) v[i] = mv[(size_t)b * NT + i];
    __syncthreads();
    for (int kkk = 0; kkk < TOPK; ++kkk) {
        float bv = -INFINITY; int bi = 0x7fffffff;
        for (int i = t; i < NT; i += 64) {
            float x = v[i];
            if (x > bv) { bv = x; bi = i; }
        }
        #pragma unroll
        for (int off = 32; off; off >>= 1) {
            float ov = __shfl_down(bv, off);
            int   oi = __shfl_down(bi, off);
            if (ov > bv || (ov == bv && oi < bi)) { bv = ov; bi = oi; }
        }
        bv = __shfl(bv, 0); bi = __shfl(bi, 0);
        if (t == 0) { topv[kkk] = bv; topi[kkk] = bi; }
        v[bi] = -INFINITY;               // all lanes write same value
        __syncthreads();
    }
    if (t == 0) {
        float m = topv[0], sum = 0.f, e[TOPK];
        #pragma unroll
        for (int i = 0; i < TOPK; ++i) { e[i] = expf(topv[i] - m); sum += e[i]; }
        #pragma unroll
        for (int i = 0; i < TOPK; ++i) wts[b * TOPK + i] = e[i] / sum;
        if (b == 0) {
            #pragma unroll
            for (int i = 0; i < TOPK; ++i) shifts[i] = topi[i];
        }
    }
}

// ---------------------------------------------------------------------------
// Kernel D: out[b,l,:] = Σ_k w[b,k] * values[b, (l+shift_k) & 1023, :]
// ---------------------------------------------------------------------------
__global__ __launch_bounds__(128) void k_out(const float* __restrict__ vals,
                                             const float* __restrict__ wts,
                                             const int* __restrict__ shifts,
                                             float* __restrict__ out) {
    __shared__ float w[TOPK];
    __shared__ int   sh[TOPK];
    const int b = blockIdx.y;
    const int l = blockIdx.x;
    const int t = threadIdx.x;
    if (t < TOPK) { w[t] = wts[b * TOPK + t]; sh[t] = shifts[t]; }
    __syncthreads();
    float4 acc = make_float4(0.f, 0.f, 0.f, 0.f);
    const float4* vb = (const float4*)(vals + (size_t)b * NL * ND);
    #pragma unroll 4
    for (int kkk = 0; kkk < TOPK; ++kkk) {
        const int sl = (l + sh[kkk]) & (NL - 1);
        const float4 x = vb[(size_t)sl * (ND / 4) + t];
        const float wk = w[kkk];
        acc.x = fmaf(wk, x.x, acc.x);
        acc.y = fmaf(wk, x.y, acc.y);
        acc.z = fmaf(wk, x.z, acc.z);
        acc.w = fmaf(wk, x.w, acc.w);
    }
    ((float4*)out)[((size_t)b * NL + l) * (ND / 4) + t] = acc;
}

extern "C" void kernel_launch(void* const* d_in, const int* in_sizes, int n_in,
                              void* d_out, int out_size, void* d_ws, size_t ws_size,
                              hipStream_t stream) {
    const float* q = (const float*)d_in[0];
    const float* k = (const float*)d_in[1];
    const float* v = (const float*)d_in[2];
    float* out    = (float*)d_out;
    float* S      = (float*)d_ws;            // NB * 1023
    float* pbar   = S + NB * 1023;           // NB * 2*NF
    float* mv     = pbar + NB * 2 * NF;      // NB * NT
    float* wts    = mv + NB * NT;            // NB * TOPK
    int*   shifts = (int*)(wts + NB * TOPK); // TOPK ints

    hipMemsetAsync(S, 0, NB * 1023 * sizeof(float), stream);
    k_gram<<<dim3(KSPLIT * 4, 4, NB), 256, 0, stream>>>(q, k, S);
    k_pdft<<<dim3(3, NB), 256, 0, stream>>>(S, pbar);
    k_mean<<<dim3((NT + 255) / 256, NB), 256, 0, stream>>>(pbar, mv);
    k_topk<<<NB, 64, 0, stream>>>(mv, wts, shifts);
    k_out<<<dim3(NL, NB), 128, 0, stream>>>(v, wts, shifts, out);
}

// Round 3
// 314.318 us; speedup vs baseline: 1.9760x; 1.0542x over previous
//
#include <hip/hip_runtime.h>
#include <math.h>

#define NB 8
#define NL 1024
#define ND 512
#define NF 513          // rfft bins of length-1024 transform
#define NT 2047         // L + S - 1
#define TOPK 20         // int(3 * log(1024))

static __device__ __forceinline__ void rot(float& c, float& s, float cf, float sf) {
    float nc = c * cf - s * sf;
    float ns = s * cf + c * sf;
    c = nc; s = ns;
}

// ---------------------------------------------------------------------------
// Kernel G: Gram GEMM  G[b][d][e] = sum_l q[b][l][d] * k[b][l][e]
// with fused diagonal-sum epilogue:  S[b][(d-e)+511] += G[b][d][e].
// Tile 128x128, 256 threads, 8x8 micro-tile (split halves), BK=32, split-K=4.
// __launch_bounds__(256,2): 256-VGPR budget so acc[8][8]+prefetch stays in
// registers (r1 shipped at 88 VGPRs -> 92 MB of scratch spill writes/dispatch).
// ---------------------------------------------------------------------------
#define BM 128
#define BN 128
#define BKG 32
#define KSPLIT 4

__global__ __launch_bounds__(256, 2) void k_gram(const float* __restrict__ q,
                                                 const float* __restrict__ kk,
                                                 float* __restrict__ S) {
    __shared__ float At[BKG][BM + 4];
    __shared__ float Bt[BKG][BN + 4];
    __shared__ float sd[255];
    const int b  = blockIdx.z;
    const int dt = blockIdx.x >> 2;      // d-tile 0..3
    const int ks = blockIdx.x & 3;       // k-split 0..3
    const int et = blockIdx.y;           // e-tile 0..3
    const int d0 = dt * BM, e0 = et * BN;
    const int tid = threadIdx.x;
    const int ti = tid >> 4;             // 0..15
    const int tj = tid & 15;             // 0..15
    const float* qb = q  + (size_t)b * NL * ND;
    const float* kb = kk + (size_t)b * NL * ND;

    const int lrow = tid >> 3;           // 0..31
    const int lc4  = tid & 7;            // 0..7

    float acc[8][8];
    #pragma unroll
    for (int i = 0; i < 8; ++i)
        #pragma unroll
        for (int j = 0; j < 8; ++j) acc[i][j] = 0.f;

    const int NITER = (NL / KSPLIT) / BKG;   // 8
    const int l0 = ks * (NL / KSPLIT);

    float4 pq[4], pk[4];
    #pragma unroll
    for (int p = 0; p < 4; ++p) {
        pq[p] = *(const float4*)&qb[(size_t)(l0 + lrow) * ND + d0 + (lc4 + 8 * p) * 4];
        pk[p] = *(const float4*)&kb[(size_t)(l0 + lrow) * ND + e0 + (lc4 + 8 * p) * 4];
    }

    for (int it = 0; it < NITER; ++it) {
        __syncthreads();
        #pragma unroll
        for (int p = 0; p < 4; ++p) {
            *(float4*)&At[lrow][(lc4 + 8 * p) * 4] = pq[p];
            *(float4*)&Bt[lrow][(lc4 + 8 * p) * 4] = pk[p];
        }
        __syncthreads();
        if (it + 1 < NITER) {
            const int l1 = l0 + (it + 1) * BKG;
            #pragma unroll
            for (int p = 0; p < 4; ++p) {
                pq[p] = *(const float4*)&qb[(size_t)(l1 + lrow) * ND + d0 + (lc4 + 8 * p) * 4];
                pk[p] = *(const float4*)&kb[(size_t)(l1 + lrow) * ND + e0 + (lc4 + 8 * p) * 4];
            }
        }
        #pragma unroll 8
        for (int c = 0; c < BKG; ++c) {
            const float4 a0 = *(const float4*)&At[c][ti * 4];
            const float4 a1 = *(const float4*)&At[c][64 + ti * 4];
            const float4 b0 = *(const float4*)&Bt[c][tj * 4];
            const float4 b1 = *(const float4*)&Bt[c][64 + tj * 4];
            const float av[8] = {a0.x, a0.y, a0.z, a0.w, a1.x, a1.y, a1.z, a1.w};
            const float bv[8] = {b0.x, b0.y, b0.z, b0.w, b1.x, b1.y, b1.z, b1.w};
            #pragma unroll
            for (int i = 0; i < 8; ++i)
                #pragma unroll
                for (int j = 0; j < 8; ++j)
                    acc[i][j] = fmaf(av[i], bv[j], acc[i][j]);
        }
    }

    // --- epilogue: reduce acc to diagonal sums ---
    for (int i = tid; i < 255; i += 256) sd[i] = 0.f;
    __syncthreads();
    // per-thread pre-reduction into 21 bins: delta = 4*(ti-tj) + (i'-j') + 64*qd
    float bin[3][7];
    #pragma unroll
    for (int s = 0; s < 3; ++s)
        #pragma unroll
        for (int u = 0; u < 7; ++u) bin[s][u] = 0.f;
    #pragma unroll
    for (int i = 0; i < 8; ++i)
        #pragma unroll
        for (int j = 0; j < 8; ++j)
            bin[(i >> 2) - (j >> 2) + 1][(i & 3) - (j & 3) + 3] += acc[i][j];
    #pragma unroll
    for (int s = 0; s < 3; ++s)
        #pragma unroll
        for (int u = 0; u < 7; ++u) {
            const int dl = 4 * (ti - tj) + (u - 3) + 64 * (s - 1);  // [-127,127]
            atomicAdd(&sd[dl + 127], bin[s][u]);
        }
    __syncthreads();
    const int doff = d0 - e0;
    for (int i = tid; i < 255; i += 256) {
        const int dg = doff + (i - 127);          // [-511,511]
        atomicAdd(&S[b * 1023 + dg + 511], sd[i]);
    }
}

// ---------------------------------------------------------------------------
// Kernel P: P̄[b][f] = sum_j S[b][j] * e^{-2πi f (j-511)/1024}, f = 0..512
// ---------------------------------------------------------------------------
__global__ __launch_bounds__(256) void k_pdft(const float* __restrict__ S,
                                              float* __restrict__ pbar) {
    __shared__ float sh[1023];
    const int b = blockIdx.y;
    const int f = blockIdx.x * 256 + threadIdx.x;
    for (int i = threadIdx.x; i < 1023; i += 256) sh[i] = S[b * 1023 + i];
    __syncthreads();
    if (f > 512) return;
    const float w = 2.0f * 3.14159265358979323846f / 1024.0f;
    float cf, sf;
    sincosf(w * (float)f, &sf, &cf);
    float c = 1.f, s = 0.f;
    float re = 0.f, im = 0.f;
    for (int j = 0; j < 1023; ++j) {
        if ((j & 63) == 0) {                      // reseed (kills drift)
            const int m = (int)(((long long)f * (long long)(j - 511)) & 1023);
            sincosf(w * (float)m, &s, &c);
        }
        const float x = sh[j];
        re = fmaf(x, c, re);
        im = fmaf(x, -s, im);
        rot(c, s, cf, sf);
    }
    pbar[b * 2 * NF + 2 * f]     = re;
    pbar[b * 2 * NF + 2 * f + 1] = im;
}

// ---------------------------------------------------------------------------
// Kernel B: mean_value[b,t] = (1/(2047*1024)) * (P̄[0] + 2Σ_{f=1..512}
//            (P̄re[f] cos(2πft/2047) - P̄im[f] sin(2πft/2047)))
// ---------------------------------------------------------------------------
__global__ __launch_bounds__(256) void k_mean(const float* __restrict__ pbar,
                                              float* __restrict__ mv) {
    __shared__ float P[2 * NF];
    const int b  = blockIdx.y;
    const int tt = blockIdx.x * 256 + threadIdx.x;
    for (int i = threadIdx.x; i < 2 * NF; i += 256)
        P[i] = pbar[(size_t)b * (2 * NF) + i];
    __syncthreads();
    if (tt >= NT) return;
    const float w = 2.0f * 3.14159265358979323846f / 2047.0f;
    float cf, sf;
    sincosf(w * (float)tt, &sf, &cf);
    float c = cf, s = sf;                 // f=1 twiddle
    float acc = P[0];
    for (int f = 1; f <= 512; ++f) {
        if ((f & 63) == 0) {
            int j = (f * tt) % 2047;
            sincosf(w * (float)j, &s, &c);
        }
        acc += 2.0f * fmaf(P[2 * f], c, -(P[2 * f + 1] * s));
        rot(c, s, cf, sf);
    }
    mv[(size_t)b * NT + tt] = acc * (1.0f / (2047.0f * 1024.0f));
}

// ---------------------------------------------------------------------------
// Kernel C: per-batch exact top-20 (descending, ties -> lower index), softmax;
// batch 0's indices become global shifts.
// ---------------------------------------------------------------------------
__global__ __launch_bounds__(64) void k_topk(const float* __restrict__ mv,
                                             float* __restrict__ wts,
                                             int* __restrict__ shifts) {
    __shared__ float v[NT];
    __shared__ float topv[TOPK];
    __shared__ int   topi[TOPK];
    const int b = blockIdx.x;
    const int t = threadIdx.x;
    for (int i = t; i < NT; i += 64) v[i] = mv[(size_t)b * NT + i];
    __syncthreads();
    for (int kkk = 0; kkk < TOPK; ++kkk) {
        float bv = -INFINITY; int bi = 0x7fffffff;
        for (int i = t; i < NT; i += 64) {
            float x = v[i];
            if (x > bv) { bv = x; bi = i; }
        }
        #pragma unroll
        for (int off = 32; off; off >>= 1) {
            float ov = __shfl_down(bv, off);
            int   oi = __shfl_down(bi, off);
            if (ov > bv || (ov == bv && oi < bi)) { bv = ov; bi = oi; }
        }
        bv = __shfl(bv, 0); bi = __shfl(bi, 0);
        if (t == 0) { topv[kkk] = bv; topi[kkk] = bi; }
        v[bi] = -INFINITY;               // all lanes write same value
        __syncthreads();
    }
    if (t == 0) {
        float m = topv[0], sum = 0.f, e[TOPK];
        #pragma unroll
        for (int i = 0; i < TOPK; ++i) { e[i] = expf(topv[i] - m); sum += e[i]; }
        #pragma unroll
        for (int i = 0; i < TOPK; ++i) wts[b * TOPK + i] = e[i] / sum;
        if (b == 0) {
            #pragma unroll
            for (int i = 0; i < TOPK; ++i) shifts[i] = topi[i];
        }
    }
}

// ---------------------------------------------------------------------------
// Kernel D: out[b,l,:] = Σ_k w[b,k] * values[b, (l+shift_k) & 1023, :]
// Flat grid with b = blockIdx.x & 7: consecutive blocks round-robin across the
// 8 XCDs, so XCD i serves only batch i -> values[b] (2.1 MB) stays L2-resident.
// ---------------------------------------------------------------------------
__global__ __launch_bounds__(128) void k_out(const float* __restrict__ vals,
                                             const float* __restrict__ wts,
                                             const int* __restrict__ shifts,
                                             float* __restrict__ out) {
    __shared__ float w[TOPK];
    __shared__ int   sh[TOPK];
    const int id = blockIdx.x;
    const int b = id & 7;                // XCD affinity
    const int l = id >> 3;
    const int t = threadIdx.x;
    if (t < TOPK) { w[t] = wts[b * TOPK + t]; sh[t] = shifts[t]; }
    __syncthreads();
    float4 acc = make_float4(0.f, 0.f, 0.f, 0.f);
    const float4* vb = (const float4*)(vals + (size_t)b * NL * ND);
    #pragma unroll 4
    for (int kkk = 0; kkk < TOPK; ++kkk) {
        const int sl = (l + sh[kkk]) & (NL - 1);
        const float4 x = vb[(size_t)sl * (ND / 4) + t];
        const float wk = w[kkk];
        acc.x = fmaf(wk, x.x, acc.x);
        acc.y = fmaf(wk, x.y, acc.y);
        acc.z = fmaf(wk, x.z, acc.z);
        acc.w = fmaf(wk, x.w, acc.w);
    }
    ((float4*)out)[((size_t)b * NL + l) * (ND / 4) + t] = acc;
}

extern "C" void kernel_launch(void* const* d_in, const int* in_sizes, int n_in,
                              void* d_out, int out_size, void* d_ws, size_t ws_size,
                              hipStream_t stream) {
    const float* q = (const float*)d_in[0];
    const float* k = (const float*)d_in[1];
    const float* v = (const float*)d_in[2];
    float* out    = (float*)d_out;
    float* S      = (float*)d_ws;            // NB * 1023
    float* pbar   = S + NB * 1023;           // NB * 2*NF
    float* mv     = pbar + NB * 2 * NF;      // NB * NT
    float* wts    = mv + NB * NT;            // NB * TOPK
    int*   shifts = (int*)(wts + NB * TOPK); // TOPK ints

    hipMemsetAsync(S, 0, NB * 1023 * sizeof(float), stream);
    k_gram<<<dim3(KSPLIT * 4, 4, NB), 256, 0, stream>>>(q, k, S);
    k_pdft<<<dim3(3, NB), 256, 0, stream>>>(S, pbar);
    k_mean<<<dim3((NT + 255) / 256, NB), 256, 0, stream>>>(pbar, mv);
    k_topk<<<NB, 64, 0, stream>>>(mv, wts, shifts);
    k_out<<<NL * NB, 128, 0, stream>>>(v, wts, shifts, out);
}

// Round 4
// 307.968 us; speedup vs baseline: 2.0168x; 1.0206x over previous
//
#include <hip/hip_runtime.h>
#include <math.h>

#define NB 8
#define NL 1024
#define ND 512
#define NF 513          // rfft bins of length-1024 transform
#define NT 2047         // L + S - 1
#define TOPK 20         // int(3 * log(1024))

typedef __attribute__((ext_vector_type(8))) short short8;
typedef __attribute__((ext_vector_type(4))) float f32x4;

static __device__ __forceinline__ void rot(float& c, float& s, float cf, float sf) {
    float nc = c * cf - s * sf;
    float ns = s * cf + c * sf;
    c = nc; s = ns;
}

static __device__ __forceinline__ unsigned short bf16_rne(float x) {
    unsigned int u = __builtin_bit_cast(unsigned int, x);
    unsigned int r = (u + 0x7fffu + ((u >> 16) & 1u)) >> 16;
    return (unsigned short)r;
}
static __device__ __forceinline__ float bf16_to_f(unsigned short h) {
    unsigned int u = ((unsigned int)h) << 16;
    return __builtin_bit_cast(float, u);
}

// ---------------------------------------------------------------------------
// Kernel T: transpose + split-bf16 convert.
// q[b][l][d] f32 -> Thi/Tlo[(which*NB+b)][d][l] bf16 (hi = rne(x), lo = rne(x-hi))
// 64x64 tiles, LDS staging, coalesced both sides.
// ---------------------------------------------------------------------------
__global__ __launch_bounds__(256) void k_tr(const float* __restrict__ q,
                                            const float* __restrict__ kk,
                                            unsigned short* __restrict__ Thi,
                                            unsigned short* __restrict__ Tlo) {
    __shared__ float tile[64][65];
    const int which = blockIdx.z;          // 0=q, 1=k
    const int b  = blockIdx.y;
    const int l0 = (blockIdx.x & 15) * 64;
    const int d0 = (blockIdx.x >> 4) * 64;
    const float* src = (which ? kk : q) + (size_t)b * NL * ND;
    const int t = threadIdx.x;
    const int r = t >> 4, c = t & 15;
    #pragma unroll
    for (int rr = 0; rr < 4; ++rr) {
        const float4 v = *(const float4*)&src[(size_t)(l0 + r + 16 * rr) * ND + d0 + c * 4];
        tile[r + 16 * rr][c * 4 + 0] = v.x;
        tile[r + 16 * rr][c * 4 + 1] = v.y;
        tile[r + 16 * rr][c * 4 + 2] = v.z;
        tile[r + 16 * rr][c * 4 + 3] = v.w;
    }
    __syncthreads();
    unsigned short* hi = Thi + ((size_t)which * NB + b) * (size_t)ND * NL;
    unsigned short* lo = Tlo + ((size_t)which * NB + b) * (size_t)ND * NL;
    #pragma unroll
    for (int p = 0; p < 2; ++p) {
        const int c2 = t + 256 * p;        // 0..511
        const int dl = c2 >> 3;            // 0..63
        const int l8 = (c2 & 7) * 8;
        short8 vh, vl;
        #pragma unroll
        for (int i = 0; i < 8; ++i) {
            const float x = tile[l8 + i][dl];
            const unsigned short h = bf16_rne(x);
            vh[i] = (short)h;
            vl[i] = (short)bf16_rne(x - bf16_to_f(h));
        }
        *(short8*)&hi[(size_t)(d0 + dl) * NL + l0 + l8] = vh;
        *(short8*)&lo[(size_t)(d0 + dl) * NL + l0 + l8] = vl;
    }
}

// ---------------------------------------------------------------------------
// Kernel G: MFMA Gram GEMM.  G[d][e] = sum_l q[l][d]*k[l][e] via split-bf16:
// G = qhi·khi^T + qhi·klo^T + qlo·khi^T  (fp32 MFMA accum; lo·lo dropped ~2^-18)
// A = qT[512][1024], B = kT[512][1024] both K-contiguous -> every fragment is
// a 16B contiguous row read. 128x128 tile, 4 waves (2x2 of 64x64), BK=64,
// split-K x2. Fused diagonal-sum epilogue into S[b][1023] via LDS + atomics.
// C layout (m89-verified): col = lane&15, row = (lane>>4)*4 + reg.
// ---------------------------------------------------------------------------
#define GBK 64

__global__ __launch_bounds__(256, 1) void k_gemm(const unsigned short* __restrict__ Thi,
                                                 const unsigned short* __restrict__ Tlo,
                                                 float* __restrict__ S) {
    __shared__ unsigned short Ahi[128][GBK];   // 16 KB each, 64 KB total
    __shared__ unsigned short Alo[128][GBK];
    __shared__ unsigned short Bhi[128][GBK];
    __shared__ unsigned short Blo[128][GBK];
    __shared__ float sd[255];
    const int b  = blockIdx.z >> 1;
    const int kh = blockIdx.z & 1;             // K-split half
    const int mt = blockIdx.x, nt = blockIdx.y;
    const int tid  = threadIdx.x;
    const int lane = tid & 63, w = tid >> 6;
    const int wr = w >> 1, wc = w & 1;         // wave -> 64x64 sub-tile
    const int m = lane & 15, g = lane >> 4;    // frag row/col + k-group

    const size_t plane = (size_t)ND * NL;
    const unsigned short* qhi = Thi + (size_t)b * plane;
    const unsigned short* khi = Thi + ((size_t)NB + b) * plane;
    const unsigned short* qlo = Tlo + (size_t)b * plane;
    const unsigned short* klo = Tlo + ((size_t)NB + b) * plane;

    f32x4 acc[4][4];
    #pragma unroll
    for (int i = 0; i < 4; ++i)
        #pragma unroll
        for (int j = 0; j < 4; ++j) acc[i][j] = (f32x4)(0.f);

    for (int kt = kh * 8; kt < kh * 8 + 8; ++kt) {
        __syncthreads();
        #pragma unroll
        for (int p = 0; p < 4; ++p) {
            const int cc  = tid + 256 * p;     // 0..1023
            const int row = cc >> 3, col8 = (cc & 7) * 8;
            const size_t ga = (size_t)(mt * 128 + row) * NL + kt * GBK + col8;
            const size_t gb = (size_t)(nt * 128 + row) * NL + kt * GBK + col8;
            *(short8*)&Ahi[row][col8] = *(const short8*)&qhi[ga];
            *(short8*)&Alo[row][col8] = *(const short8*)&qlo[ga];
            *(short8*)&Bhi[row][col8] = *(const short8*)&khi[gb];
            *(short8*)&Blo[row][col8] = *(const short8*)&klo[gb];
        }
        __syncthreads();
        #pragma unroll
        for (int ks = 0; ks < 2; ++ks) {
            short8 ah[4], al[4], bh[4], bl[4];
            #pragma unroll
            for (int i = 0; i < 4; ++i) {
                ah[i] = *(const short8*)&Ahi[wr * 64 + i * 16 + m][ks * 32 + g * 8];
                al[i] = *(const short8*)&Alo[wr * 64 + i * 16 + m][ks * 32 + g * 8];
            }
            #pragma unroll
            for (int j = 0; j < 4; ++j) {
                bh[j] = *(const short8*)&Bhi[wc * 64 + j * 16 + m][ks * 32 + g * 8];
                bl[j] = *(const short8*)&Blo[wc * 64 + j * 16 + m][ks * 32 + g * 8];
            }
            #pragma unroll
            for (int i = 0; i < 4; ++i)
                #pragma unroll
                for (int j = 0; j < 4; ++j) {
                    acc[i][j] = __builtin_amdgcn_mfma_f32_16x16x32_bf16(ah[i], bh[j], acc[i][j], 0, 0, 0);
                    acc[i][j] = __builtin_amdgcn_mfma_f32_16x16x32_bf16(ah[i], bl[j], acc[i][j], 0, 0, 0);
                    acc[i][j] = __builtin_amdgcn_mfma_f32_16x16x32_bf16(al[i], bh[j], acc[i][j], 0, 0, 0);
                }
        }
    }

    // --- epilogue: diagonal sums. delta = row - col (global: + (mt-nt)*128) ---
    if (tid < 255) sd[tid] = 0.f;
    __syncthreads();
    float bin[7][4];
    #pragma unroll
    for (int u = 0; u < 7; ++u)
        #pragma unroll
        for (int r2 = 0; r2 < 4; ++r2) bin[u][r2] = 0.f;
    #pragma unroll
    for (int i = 0; i < 4; ++i)
        #pragma unroll
        for (int j = 0; j < 4; ++j)
            #pragma unroll
            for (int r2 = 0; r2 < 4; ++r2) bin[i - j + 3][r2] += acc[i][j][r2];
    const int basei = (wr - wc) * 64 + g * 4 - m + 127;
    #pragma unroll
    for (int u = 0; u < 7; ++u)
        #pragma unroll
        for (int r2 = 0; r2 < 4; ++r2)
            atomicAdd(&sd[basei + (u - 3) * 16 + r2], bin[u][r2]);
    __syncthreads();
    const int doff = (mt - nt) * 128 + 511 - 127;
    if (tid < 255) atomicAdd(&S[b * 1023 + doff + tid], sd[tid]);
}

// ---------------------------------------------------------------------------
// Kernel P: P̄[b][f] = sum_j S[b][j] * e^{-2πi f (j-511)/1024}, f = 0..512
// ---------------------------------------------------------------------------
__global__ __launch_bounds__(256) void k_pdft(const float* __restrict__ S,
                                              float* __restrict__ pbar) {
    __shared__ float sh[1023];
    const int b = blockIdx.y;
    const int f = blockIdx.x * 256 + threadIdx.x;
    for (int i = threadIdx.x; i < 1023; i += 256) sh[i] = S[b * 1023 + i];
    __syncthreads();
    if (f > 512) return;
    const float w = 2.0f * 3.14159265358979323846f / 1024.0f;
    float cf, sf;
    sincosf(w * (float)f, &sf, &cf);
    float c = 1.f, s = 0.f;
    float re = 0.f, im = 0.f;
    for (int j = 0; j < 1023; ++j) {
        if ((j & 63) == 0) {                      // reseed (kills drift)
            const int m = (int)(((long long)f * (long long)(j - 511)) & 1023);
            sincosf(w * (float)m, &s, &c);
        }
        const float x = sh[j];
        re = fmaf(x, c, re);
        im = fmaf(x, -s, im);
        rot(c, s, cf, sf);
    }
    pbar[b * 2 * NF + 2 * f]     = re;
    pbar[b * 2 * NF + 2 * f + 1] = im;
}

// ---------------------------------------------------------------------------
// Kernel B: mean_value[b,t] = (1/(2047*1024)) * (P̄[0] + 2Σ_{f=1..512}
//            (P̄re[f] cos(2πft/2047) - P̄im[f] sin(2πft/2047)))
// ---------------------------------------------------------------------------
__global__ __launch_bounds__(256) void k_mean(const float* __restrict__ pbar,
                                              float* __restrict__ mv) {
    __shared__ float P[2 * NF];
    const int b  = blockIdx.y;
    const int tt = blockIdx.x * 256 + threadIdx.x;
    for (int i = threadIdx.x; i < 2 * NF; i += 256)
        P[i] = pbar[(size_t)b * (2 * NF) + i];
    __syncthreads();
    if (tt >= NT) return;
    const float w = 2.0f * 3.14159265358979323846f / 2047.0f;
    float cf, sf;
    sincosf(w * (float)tt, &sf, &cf);
    float c = cf, s = sf;                 // f=1 twiddle
    float acc = P[0];
    for (int f = 1; f <= 512; ++f) {
        if ((f & 63) == 0) {
            int j = (f * tt) % 2047;
            sincosf(w * (float)j, &s, &c);
        }
        acc += 2.0f * fmaf(P[2 * f], c, -(P[2 * f + 1] * s));
        rot(c, s, cf, sf);
    }
    mv[(size_t)b * NT + tt] = acc * (1.0f / (2047.0f * 1024.0f));
}

// ---------------------------------------------------------------------------
// Kernel C: per-batch exact top-20 (set semantics; order-invariant downstream),
// softmax; batch 0's indices become global shifts.
// ---------------------------------------------------------------------------
__global__ __launch_bounds__(64) void k_topk(const float* __restrict__ mv,
                                             float* __restrict__ wts,
                                             int* __restrict__ shifts) {
    __shared__ float v[NT];
    __shared__ float topv[TOPK];
    __shared__ int   topi[TOPK];
    const int b = blockIdx.x;
    const int t = threadIdx.x;
    for (int i = t; i < NT; i += 64) v[i] = mv[(size_t)b * NT + i];
    __syncthreads();
    for (int kkk = 0; kkk < TOPK; ++kkk) {
        float bv = -INFINITY; int bi = 0x7fffffff;
        for (int i = t; i < NT; i += 64) {
            float x = v[i];
            if (x > bv) { bv = x; bi = i; }
        }
        #pragma unroll
        for (int off = 32; off; off >>= 1) {
            float ov = __shfl_down(bv, off);
            int   oi = __shfl_down(bi, off);
            if (ov > bv || (ov == bv && oi < bi)) { bv = ov; bi = oi; }
        }
        bv = __shfl(bv, 0); bi = __shfl(bi, 0);
        if (t == 0) { topv[kkk] = bv; topi[kkk] = bi; }
        v[bi] = -INFINITY;               // all lanes write same value
        __syncthreads();
    }
    if (t == 0) {
        float m = topv[0], sum = 0.f, e[TOPK];
        #pragma unroll
        for (int i = 0; i < TOPK; ++i) { e[i] = expf(topv[i] - m); sum += e[i]; }
        #pragma unroll
        for (int i = 0; i < TOPK; ++i) wts[b * TOPK + i] = e[i] / sum;
        if (b == 0) {
            #pragma unroll
            for (int i = 0; i < TOPK; ++i) shifts[i] = topi[i];
        }
    }
}

// ---------------------------------------------------------------------------
// Kernel D: out[b,l,:] = Σ_k w[b,k] * values[b, (l+shift_k) & 1023, :]
// b = blockIdx.x & 7: XCD affinity so values[b] (2.1 MB) stays L2-resident.
// ---------------------------------------------------------------------------
__global__ __launch_bounds__(128) void k_out(const float* __restrict__ vals,
                                             const float* __restrict__ wts,
                                             const int* __restrict__ shifts,
                                             float* __restrict__ out) {
    __shared__ float w[TOPK];
    __shared__ int   sh[TOPK];
    const int id = blockIdx.x;
    const int b = id & 7;                // XCD affinity
    const int l = id >> 3;
    const int t = threadIdx.x;
    if (t < TOPK) { w[t] = wts[b * TOPK + t]; sh[t] = shifts[t]; }
    __syncthreads();
    float4 acc = make_float4(0.f, 0.f, 0.f, 0.f);
    const float4* vb = (const float4*)(vals + (size_t)b * NL * ND);
    #pragma unroll 4
    for (int kkk = 0; kkk < TOPK; ++kkk) {
        const int sl = (l + sh[kkk]) & (NL - 1);
        const float4 x = vb[(size_t)sl * (ND / 4) + t];
        const float wk = w[kkk];
        acc.x = fmaf(wk, x.x, acc.x);
        acc.y = fmaf(wk, x.y, acc.y);
        acc.z = fmaf(wk, x.z, acc.z);
        acc.w = fmaf(wk, x.w, acc.w);
    }
    ((float4*)out)[((size_t)b * NL + l) * (ND / 4) + t] = acc;
}

extern "C" void kernel_launch(void* const* d_in, const int* in_sizes, int n_in,
                              void* d_out, int out_size, void* d_ws, size_t ws_size,
                              hipStream_t stream) {
    const float* q = (const float*)d_in[0];
    const float* k = (const float*)d_in[1];
    const float* v = (const float*)d_in[2];
    float* out    = (float*)d_out;

    const size_t plane = (size_t)ND * NL;                 // 512*1024
    unsigned short* Thi = (unsigned short*)d_ws;          // 2*NB planes bf16
    unsigned short* Tlo = Thi + 2 * NB * plane;           // 2*NB planes bf16
    float* S      = (float*)(Tlo + 2 * NB * plane);       // NB * 1023
    float* pbar   = S + NB * 1023;                        // NB * 2*NF
    float* mv     = pbar + NB * 2 * NF;                   // NB * NT
    float* wts    = mv + NB * NT;                         // NB * TOPK
    int*   shifts = (int*)(wts + NB * TOPK);              // TOPK ints

    hipMemsetAsync(S, 0, NB * 1023 * sizeof(float), stream);
    k_tr  <<<dim3(128, NB, 2), 256, 0, stream>>>(q, k, Thi, Tlo);
    k_gemm<<<dim3(4, 4, NB * 2), 256, 0, stream>>>(Thi, Tlo, S);
    k_pdft<<<dim3(3, NB), 256, 0, stream>>>(S, pbar);
    k_mean<<<dim3((NT + 255) / 256, NB), 256, 0, stream>>>(pbar, mv);
    k_topk<<<NB, 64, 0, stream>>>(mv, wts, shifts);
    k_out <<<NL * NB, 128, 0, stream>>>(v, wts, shifts, out);
}

// Round 5
// 220.706 us; speedup vs baseline: 2.8141x; 1.3954x over previous
//
#include <hip/hip_runtime.h>
#include <math.h>

#define NB 8
#define NL 1024
#define ND 512
#define NF 513          // rfft bins of length-1024 transform
#define NT 2047         // L + S - 1
#define TOPK 20         // int(3 * log(1024))

typedef __attribute__((ext_vector_type(8))) short short8;
typedef __attribute__((ext_vector_type(4))) float f32x4;

static __device__ __forceinline__ unsigned short bf16_rne(float x) {
    unsigned int u = __builtin_bit_cast(unsigned int, x);
    unsigned int r = (u + 0x7fffu + ((u >> 16) & 1u)) >> 16;
    return (unsigned short)r;
}
static __device__ __forceinline__ float bf16_to_f(unsigned short h) {
    unsigned int u = ((unsigned int)h) << 16;
    return __builtin_bit_cast(float, u);
}

// ---------------------------------------------------------------------------
// Kernel T: transpose + split-bf16 convert.
// q[b][l][d] f32 -> Thi/Tlo[(which*NB+b)][d][l] bf16 (hi = rne(x), lo = rne(x-hi))
// ---------------------------------------------------------------------------
__global__ __launch_bounds__(256) void k_tr(const float* __restrict__ q,
                                            const float* __restrict__ kk,
                                            unsigned short* __restrict__ Thi,
                                            unsigned short* __restrict__ Tlo) {
    __shared__ float tile[64][65];
    const int which = blockIdx.z;          // 0=q, 1=k
    const int b  = blockIdx.y;
    const int l0 = (blockIdx.x & 15) * 64;
    const int d0 = (blockIdx.x >> 4) * 64;
    const float* src = (which ? kk : q) + (size_t)b * NL * ND;
    const int t = threadIdx.x;
    const int r = t >> 4, c = t & 15;
    #pragma unroll
    for (int rr = 0; rr < 4; ++rr) {
        const float4 v = *(const float4*)&src[(size_t)(l0 + r + 16 * rr) * ND + d0 + c * 4];
        tile[r + 16 * rr][c * 4 + 0] = v.x;
        tile[r + 16 * rr][c * 4 + 1] = v.y;
        tile[r + 16 * rr][c * 4 + 2] = v.z;
        tile[r + 16 * rr][c * 4 + 3] = v.w;
    }
    __syncthreads();
    unsigned short* hi = Thi + ((size_t)which * NB + b) * (size_t)ND * NL;
    unsigned short* lo = Tlo + ((size_t)which * NB + b) * (size_t)ND * NL;
    #pragma unroll
    for (int p = 0; p < 2; ++p) {
        const int c2 = t + 256 * p;        // 0..511
        const int dl = c2 >> 3;            // 0..63
        const int l8 = (c2 & 7) * 8;
        short8 vh, vl;
        #pragma unroll
        for (int i = 0; i < 8; ++i) {
            const float x = tile[l8 + i][dl];
            const unsigned short h = bf16_rne(x);
            vh[i] = (short)h;
            vl[i] = (short)bf16_rne(x - bf16_to_f(h));
        }
        *(short8*)&hi[(size_t)(d0 + dl) * NL + l0 + l8] = vh;
        *(short8*)&lo[(size_t)(d0 + dl) * NL + l0 + l8] = vl;
    }
}

// ---------------------------------------------------------------------------
// Kernel G: MFMA Gram GEMM.  G = qhi·khi^T + qhi·klo^T + qlo·khi^T.
// 128x128 tile, 4 waves (2x2 of 64x64), BK=64, split-K x2, fused diag-sum.
// LDS tiles padded to GBK+8 shorts/row (144 B = 36 words): consecutive rows
// advance 4 banks, so the 16 same-column lanes of each ds_read_b128 g-group
// spread uniformly (r4's unpadded 128 B stride was a 16-way read conflict).
// ---------------------------------------------------------------------------
#define GBK 64
#define GPAD 8

__global__ __launch_bounds__(256, 1) void k_gemm(const unsigned short* __restrict__ Thi,
                                                 const unsigned short* __restrict__ Tlo,
                                                 float* __restrict__ S) {
    __shared__ unsigned short Ahi[128][GBK + GPAD];
    __shared__ unsigned short Alo[128][GBK + GPAD];
    __shared__ unsigned short Bhi[128][GBK + GPAD];
    __shared__ unsigned short Blo[128][GBK + GPAD];
    __shared__ float sd[255];
    const int b  = blockIdx.z >> 1;
    const int kh = blockIdx.z & 1;             // K-split half
    const int mt = blockIdx.x, nt = blockIdx.y;
    const int tid  = threadIdx.x;
    const int lane = tid & 63, w = tid >> 6;
    const int wr = w >> 1, wc = w & 1;         // wave -> 64x64 sub-tile
    const int m = lane & 15, g = lane >> 4;    // frag row/col + k-group

    const size_t plane = (size_t)ND * NL;
    const unsigned short* qhi = Thi + (size_t)b * plane;
    const unsigned short* khi = Thi + ((size_t)NB + b) * plane;
    const unsigned short* qlo = Tlo + (size_t)b * plane;
    const unsigned short* klo = Tlo + ((size_t)NB + b) * plane;

    f32x4 acc[4][4];
    #pragma unroll
    for (int i = 0; i < 4; ++i)
        #pragma unroll
        for (int j = 0; j < 4; ++j) acc[i][j] = (f32x4)(0.f);

    for (int kt = kh * 8; kt < kh * 8 + 8; ++kt) {
        __syncthreads();
        #pragma unroll
        for (int p = 0; p < 4; ++p) {
            const int cc  = tid + 256 * p;     // 0..1023
            const int row = cc >> 3, col8 = (cc & 7) * 8;
            const size_t ga = (size_t)(mt * 128 + row) * NL + kt * GBK + col8;
            const size_t gb = (size_t)(nt * 128 + row) * NL + kt * GBK + col8;
            *(short8*)&Ahi[row][col8] = *(const short8*)&qhi[ga];
            *(short8*)&Alo[row][col8] = *(const short8*)&qlo[ga];
            *(short8*)&Bhi[row][col8] = *(const short8*)&khi[gb];
            *(short8*)&Blo[row][col8] = *(const short8*)&klo[gb];
        }
        __syncthreads();
        #pragma unroll
        for (int ks = 0; ks < 2; ++ks) {
            short8 ah[4], al[4], bh[4], bl[4];
            #pragma unroll
            for (int i = 0; i < 4; ++i) {
                ah[i] = *(const short8*)&Ahi[wr * 64 + i * 16 + m][ks * 32 + g * 8];
                al[i] = *(const short8*)&Alo[wr * 64 + i * 16 + m][ks * 32 + g * 8];
            }
            #pragma unroll
            for (int j = 0; j < 4; ++j) {
                bh[j] = *(const short8*)&Bhi[wc * 64 + j * 16 + m][ks * 32 + g * 8];
                bl[j] = *(const short8*)&Blo[wc * 64 + j * 16 + m][ks * 32 + g * 8];
            }
            #pragma unroll
            for (int i = 0; i < 4; ++i)
                #pragma unroll
                for (int j = 0; j < 4; ++j) {
                    acc[i][j] = __builtin_amdgcn_mfma_f32_16x16x32_bf16(ah[i], bh[j], acc[i][j], 0, 0, 0);
                    acc[i][j] = __builtin_amdgcn_mfma_f32_16x16x32_bf16(ah[i], bl[j], acc[i][j], 0, 0, 0);
                    acc[i][j] = __builtin_amdgcn_mfma_f32_16x16x32_bf16(al[i], bh[j], acc[i][j], 0, 0, 0);
                }
        }
    }

    // --- epilogue: diagonal sums. delta = row - col (global: + (mt-nt)*128) ---
    if (tid < 255) sd[tid] = 0.f;
    __syncthreads();
    float bin[7][4];
    #pragma unroll
    for (int u = 0; u < 7; ++u)
        #pragma unroll
        for (int r2 = 0; r2 < 4; ++r2) bin[u][r2] = 0.f;
    #pragma unroll
    for (int i = 0; i < 4; ++i)
        #pragma unroll
        for (int j = 0; j < 4; ++j)
            #pragma unroll
            for (int r2 = 0; r2 < 4; ++r2) bin[i - j + 3][r2] += acc[i][j][r2];
    const int basei = (wr - wc) * 64 + g * 4 - m + 127;
    #pragma unroll
    for (int u = 0; u < 7; ++u)
        #pragma unroll
        for (int r2 = 0; r2 < 4; ++r2)
            atomicAdd(&sd[basei + (u - 3) * 16 + r2], bin[u][r2]);
    __syncthreads();
    const int doff = (mt - nt) * 128 + 511 - 127;
    if (tid < 255) atomicAdd(&S[b * 1023 + doff + tid], sd[tid]);
}

// ---------------------------------------------------------------------------
// Kernel P: P̄[b][f] = sum_j S[b][j] e^{-2πi f (j-511)/1024}.
// One wave per (b,f): lanes split j, exact sincosf per term, butterfly reduce.
// (r4 version: 24 blocks, 0.7% occupancy, 73 µs.)
// ---------------------------------------------------------------------------
__global__ __launch_bounds__(64) void k_pdft(const float* __restrict__ S,
                                             float* __restrict__ pbar) {
    const int b = blockIdx.y;
    const int f = blockIdx.x;              // 0..512
    const int lane = threadIdx.x;
    const float w = 2.0f * 3.14159265358979323846f / 1024.0f;
    float re = 0.f, im = 0.f;
    #pragma unroll
    for (int i = 0; i < 16; ++i) {
        const int j = lane + 64 * i;
        if (j < 1023) {
            const int mm = (f * (j - 511)) & 1023;   // exact mod (pow2, two's compl.)
            float s, c;
            sincosf(w * (float)mm, &s, &c);
            const float x = S[b * 1023 + j];
            re = fmaf(x, c, re);
            im = fmaf(x, -s, im);
        }
    }
    #pragma unroll
    for (int off = 32; off; off >>= 1) {
        re += __shfl_xor(re, off);
        im += __shfl_xor(im, off);
    }
    if (lane == 0) {
        pbar[b * 2 * NF + 2 * f]     = re;
        pbar[b * 2 * NF + 2 * f + 1] = im;
    }
}

// ---------------------------------------------------------------------------
// Kernel B: mean_value[b,t] = (1/(2047*1024)) * (P̄[0] + 2Σ_{f=1..512}
//            (P̄re[f] cos(2πft/2047) - P̄im[f] sin(2πft/2047)))
// One wave per (b,t), 4 waves/block; lanes split f, butterfly reduce.
// ---------------------------------------------------------------------------
__global__ __launch_bounds__(256) void k_mean(const float* __restrict__ pbar,
                                              float* __restrict__ mv) {
    __shared__ float P[2 * NF];
    const int b = blockIdx.y;
    for (int i = threadIdx.x; i < 2 * NF; i += 256)
        P[i] = pbar[(size_t)b * (2 * NF) + i];
    __syncthreads();
    const int wave = threadIdx.x >> 6, lane = threadIdx.x & 63;
    const int t = blockIdx.x * 4 + wave;   // 0..2047
    if (t >= NT) return;
    const float w2 = 2.0f * 3.14159265358979323846f / 2047.0f;
    float acc = 0.f;
    #pragma unroll
    for (int i = 0; i < 8; ++i) {
        const int f = 1 + lane + 64 * i;   // covers 1..512 exactly
        const int mm = (f * t) % 2047;
        float s, c;
        sincosf(w2 * (float)mm, &s, &c);
        acc = fmaf(P[2 * f], c, acc);
        acc = fmaf(-P[2 * f + 1], s, acc);
    }
    acc *= 2.0f;
    #pragma unroll
    for (int off = 32; off; off >>= 1) acc += __shfl_xor(acc, off);
    if (lane == 0)
        mv[(size_t)b * NT + t] = (acc + P[0]) * (1.0f / (2047.0f * 1024.0f));
}

// ---------------------------------------------------------------------------
// Kernel C: per-batch exact top-20, softmax; batch 0's indices -> shifts.
// ---------------------------------------------------------------------------
__global__ __launch_bounds__(64) void k_topk(const float* __restrict__ mv,
                                             float* __restrict__ wts,
                                             int* __restrict__ shifts) {
    __shared__ float v[NT];
    __shared__ float topv[TOPK];
    __shared__ int   topi[TOPK];
    const int b = blockIdx.x;
    const int t = threadIdx.x;
    for (int i = t; i < NT; i += 64) v[i] = mv[(size_t)b * NT + i];
    __syncthreads();
    for (int kkk = 0; kkk < TOPK; ++kkk) {
        float bv = -INFINITY; int bi = 0x7fffffff;
        for (int i = t; i < NT; i += 64) {
            float x = v[i];
            if (x > bv) { bv = x; bi = i; }
        }
        #pragma unroll
        for (int off = 32; off; off >>= 1) {
            float ov = __shfl_down(bv, off);
            int   oi = __shfl_down(bi, off);
            if (ov > bv || (ov == bv && oi < bi)) { bv = ov; bi = oi; }
        }
        bv = __shfl(bv, 0); bi = __shfl(bi, 0);
        if (t == 0) { topv[kkk] = bv; topi[kkk] = bi; }
        v[bi] = -INFINITY;               // all lanes write same value
        __syncthreads();
    }
    if (t == 0) {
        float m = topv[0], sum = 0.f, e[TOPK];
        #pragma unroll
        for (int i = 0; i < TOPK; ++i) { e[i] = expf(topv[i] - m); sum += e[i]; }
        #pragma unroll
        for (int i = 0; i < TOPK; ++i) wts[b * TOPK + i] = e[i] / sum;
        if (b == 0) {
            #pragma unroll
            for (int i = 0; i < TOPK; ++i) shifts[i] = topi[i];
        }
    }
}

// ---------------------------------------------------------------------------
// Kernel D: out[b,l,:] = Σ_k w[b,k] * values[b, (l+shift_k) & 1023, :]
// b = blockIdx.x & 7: XCD affinity so values[b] (2.1 MB) stays L2-resident.
// ---------------------------------------------------------------------------
__global__ __launch_bounds__(128) void k_out(const float* __restrict__ vals,
                                             const float* __restrict__ wts,
                                             const int* __restrict__ shifts,
                                             float* __restrict__ out) {
    __shared__ float w[TOPK];
    __shared__ int   sh[TOPK];
    const int id = blockIdx.x;
    const int b = id & 7;                // XCD affinity
    const int l = id >> 3;
    const int t = threadIdx.x;
    if (t < TOPK) { w[t] = wts[b * TOPK + t]; sh[t] = shifts[t]; }
    __syncthreads();
    float4 acc = make_float4(0.f, 0.f, 0.f, 0.f);
    const float4* vb = (const float4*)(vals + (size_t)b * NL * ND);
    #pragma unroll 4
    for (int kkk = 0; kkk < TOPK; ++kkk) {
        const int sl = (l + sh[kkk]) & (NL - 1);
        const float4 x = vb[(size_t)sl * (ND / 4) + t];
        const float wk = w[kkk];
        acc.x = fmaf(wk, x.x, acc.x);
        acc.y = fmaf(wk, x.y, acc.y);
        acc.z = fmaf(wk, x.z, acc.z);
        acc.w = fmaf(wk, x.w, acc.w);
    }
    ((float4*)out)[((size_t)b * NL + l) * (ND / 4) + t] = acc;
}

extern "C" void kernel_launch(void* const* d_in, const int* in_sizes, int n_in,
                              void* d_out, int out_size, void* d_ws, size_t ws_size,
                              hipStream_t stream) {
    const float* q = (const float*)d_in[0];
    const float* k = (const float*)d_in[1];
    const float* v = (const float*)d_in[2];
    float* out    = (float*)d_out;

    const size_t plane = (size_t)ND * NL;                 // 512*1024
    unsigned short* Thi = (unsigned short*)d_ws;          // 2*NB planes bf16
    unsigned short* Tlo = Thi + 2 * NB * plane;           // 2*NB planes bf16
    float* S      = (float*)(Tlo + 2 * NB * plane);       // NB * 1023
    float* pbar   = S + NB * 1023;                        // NB * 2*NF
    float* mv     = pbar + NB * 2 * NF;                   // NB * NT
    float* wts    = mv + NB * NT;                         // NB * TOPK
    int*   shifts = (int*)(wts + NB * TOPK);              // TOPK ints

    hipMemsetAsync(S, 0, NB * 1023 * sizeof(float), stream);
    k_tr  <<<dim3(128, NB, 2), 256, 0, stream>>>(q, k, Thi, Tlo);
    k_gemm<<<dim3(4, 4, NB * 2), 256, 0, stream>>>(Thi, Tlo, S);
    k_pdft<<<dim3(NF, NB), 64, 0, stream>>>(S, pbar);
    k_mean<<<dim3(512, NB), 256, 0, stream>>>(pbar, mv);
    k_topk<<<NB, 64, 0, stream>>>(mv, wts, shifts);
    k_out <<<NL * NB, 128, 0, stream>>>(v, wts, shifts, out);
}

// Round 6
// 185.151 us; speedup vs baseline: 3.3546x; 1.1920x over previous
//
#include <hip/hip_runtime.h>
#include <math.h>

#define NB 8
#define NL 1024
#define ND 512
#define NF 513          // rfft bins of length-1024 transform
#define NT 2047         // L + S - 1
#define TOPK 20         // int(3 * log(1024))

typedef __attribute__((ext_vector_type(8))) short short8;
typedef __attribute__((ext_vector_type(4))) float f32x4;

static __device__ __forceinline__ unsigned short bf16_rne(float x) {
    unsigned int u = __builtin_bit_cast(unsigned int, x);
    unsigned int r = (u + 0x7fffu + ((u >> 16) & 1u)) >> 16;
    return (unsigned short)r;
}
static __device__ __forceinline__ float bf16_to_f(unsigned short h) {
    unsigned int u = ((unsigned int)h) << 16;
    return __builtin_bit_cast(float, u);
}

// ---------------------------------------------------------------------------
// Kernel T: transpose + split-bf16 convert.
// q[b][l][d] f32 -> Thi/Tlo[(which*NB+b)][d][l] bf16 (hi = rne(x), lo = rne(x-hi))
// ---------------------------------------------------------------------------
__global__ __launch_bounds__(256) void k_tr(const float* __restrict__ q,
                                            const float* __restrict__ kk,
                                            unsigned short* __restrict__ Thi,
                                            unsigned short* __restrict__ Tlo) {
    __shared__ float tile[64][65];
    const int which = blockIdx.z;          // 0=q, 1=k
    const int b  = blockIdx.y;
    const int l0 = (blockIdx.x & 15) * 64;
    const int d0 = (blockIdx.x >> 4) * 64;
    const float* src = (which ? kk : q) + (size_t)b * NL * ND;
    const int t = threadIdx.x;
    const int r = t >> 4, c = t & 15;
    #pragma unroll
    for (int rr = 0; rr < 4; ++rr) {
        const float4 v = *(const float4*)&src[(size_t)(l0 + r + 16 * rr) * ND + d0 + c * 4];
        tile[r + 16 * rr][c * 4 + 0] = v.x;
        tile[r + 16 * rr][c * 4 + 1] = v.y;
        tile[r + 16 * rr][c * 4 + 2] = v.z;
        tile[r + 16 * rr][c * 4 + 3] = v.w;
    }
    __syncthreads();
    unsigned short* hi = Thi + ((size_t)which * NB + b) * (size_t)ND * NL;
    unsigned short* lo = Tlo + ((size_t)which * NB + b) * (size_t)ND * NL;
    #pragma unroll
    for (int p = 0; p < 2; ++p) {
        const int c2 = t + 256 * p;        // 0..511
        const int dl = c2 >> 3;            // 0..63
        const int l8 = (c2 & 7) * 8;
        short8 vh, vl;
        #pragma unroll
        for (int i = 0; i < 8; ++i) {
            const float x = tile[l8 + i][dl];
            const unsigned short h = bf16_rne(x);
            vh[i] = (short)h;
            vl[i] = (short)bf16_rne(x - bf16_to_f(h));
        }
        *(short8*)&hi[(size_t)(d0 + dl) * NL + l0 + l8] = vh;
        *(short8*)&lo[(size_t)(d0 + dl) * NL + l0 + l8] = vl;
    }
}

// ---------------------------------------------------------------------------
// Kernel G: MFMA Gram GEMM.  G = qhi·khi^T + qhi·klo^T + qlo·khi^T.
// r5 post-mortem: 1 block/CU -> pure latency exposure (all pipes <11%).
// Now: flat 512-block grid (split-K x4), 76 KB LDS -> 2 blocks/CU; register
// prefetch of the next K-step overlaps global latency with MFMA; batch-
// affinity decode (b = id&7) pins each batch to one XCD's L2 for input reuse
// and S-atomics; per-wave sd slices remove same-address LDS-atomic collisions.
// ---------------------------------------------------------------------------
#define GBK 64
#define GPAD 8
#define GKT 4            // K-steps per block (K = 256 per block)

__global__ __launch_bounds__(256, 2) void k_gemm(const unsigned short* __restrict__ Thi,
                                                 const unsigned short* __restrict__ Tlo,
                                                 float* __restrict__ S) {
    __shared__ unsigned short Ahi[128][GBK + GPAD];
    __shared__ unsigned short Alo[128][GBK + GPAD];
    __shared__ unsigned short Bhi[128][GBK + GPAD];
    __shared__ unsigned short Blo[128][GBK + GPAD];
    __shared__ float sd4[4][256];
    const int id   = blockIdx.x;
    const int b    = id & 7;                   // XCD affinity by batch
    const int rest = id >> 3;                  // 0..63
    const int mt = rest & 3, nt = (rest >> 2) & 3, kq = rest >> 4;
    const int tid  = threadIdx.x;
    const int lane = tid & 63, w = tid >> 6;
    const int wr = w >> 1, wc = w & 1;         // wave -> 64x64 sub-tile
    const int m = lane & 15, g = lane >> 4;    // frag row/col + k-group

    const size_t plane = (size_t)ND * NL;
    const unsigned short* qhi = Thi + (size_t)b * plane;
    const unsigned short* khi = Thi + ((size_t)NB + b) * plane;
    const unsigned short* qlo = Tlo + (size_t)b * plane;
    const unsigned short* klo = Tlo + ((size_t)NB + b) * plane;

    f32x4 acc[4][4];
    #pragma unroll
    for (int i = 0; i < 4; ++i)
        #pragma unroll
        for (int j = 0; j < 4; ++j) acc[i][j] = (f32x4)(0.f);

    const int kbase = kq * GKT;
    short8 r_ah[4], r_al[4], r_bh[4], r_bl[4];
    #pragma unroll
    for (int p = 0; p < 4; ++p) {
        const int cc  = tid + 256 * p;
        const int row = cc >> 3, col8 = (cc & 7) * 8;
        const size_t ga = (size_t)(mt * 128 + row) * NL + kbase * GBK + col8;
        const size_t gb = (size_t)(nt * 128 + row) * NL + kbase * GBK + col8;
        r_ah[p] = *(const short8*)&qhi[ga];
        r_al[p] = *(const short8*)&qlo[ga];
        r_bh[p] = *(const short8*)&khi[gb];
        r_bl[p] = *(const short8*)&klo[gb];
    }

    for (int kt = 0; kt < GKT; ++kt) {
        __syncthreads();
        #pragma unroll
        for (int p = 0; p < 4; ++p) {
            const int cc  = tid + 256 * p;
            const int row = cc >> 3, col8 = (cc & 7) * 8;
            *(short8*)&Ahi[row][col8] = r_ah[p];
            *(short8*)&Alo[row][col8] = r_al[p];
            *(short8*)&Bhi[row][col8] = r_bh[p];
            *(short8*)&Blo[row][col8] = r_bl[p];
        }
        __syncthreads();
        if (kt + 1 < GKT) {                    // prefetch next K-step; lands
            #pragma unroll                     // during the MFMA phase below
            for (int p = 0; p < 4; ++p) {
                const int cc  = tid + 256 * p;
                const int row = cc >> 3, col8 = (cc & 7) * 8;
                const size_t ga = (size_t)(mt * 128 + row) * NL + (kbase + kt + 1) * GBK + col8;
                const size_t gb = (size_t)(nt * 128 + row) * NL + (kbase + kt + 1) * GBK + col8;
                r_ah[p] = *(const short8*)&qhi[ga];
                r_al[p] = *(const short8*)&qlo[ga];
                r_bh[p] = *(const short8*)&khi[gb];
                r_bl[p] = *(const short8*)&klo[gb];
            }
        }
        #pragma unroll
        for (int ks = 0; ks < 2; ++ks) {
            short8 ah[4], al[4], bh[4], bl[4];
            #pragma unroll
            for (int i = 0; i < 4; ++i) {
                ah[i] = *(const short8*)&Ahi[wr * 64 + i * 16 + m][ks * 32 + g * 8];
                al[i] = *(const short8*)&Alo[wr * 64 + i * 16 + m][ks * 32 + g * 8];
            }
            #pragma unroll
            for (int j = 0; j < 4; ++j) {
                bh[j] = *(const short8*)&Bhi[wc * 64 + j * 16 + m][ks * 32 + g * 8];
                bl[j] = *(const short8*)&Blo[wc * 64 + j * 16 + m][ks * 32 + g * 8];
            }
            #pragma unroll
            for (int i = 0; i < 4; ++i)
                #pragma unroll
                for (int j = 0; j < 4; ++j) {
                    acc[i][j] = __builtin_amdgcn_mfma_f32_16x16x32_bf16(ah[i], bh[j], acc[i][j], 0, 0, 0);
                    acc[i][j] = __builtin_amdgcn_mfma_f32_16x16x32_bf16(ah[i], bl[j], acc[i][j], 0, 0, 0);
                    acc[i][j] = __builtin_amdgcn_mfma_f32_16x16x32_bf16(al[i], bh[j], acc[i][j], 0, 0, 0);
                }
        }
    }

    // --- epilogue: diagonal sums. delta = row - col (global: + (mt-nt)*128) ---
    for (int i = tid; i < 1024; i += 256) ((float*)sd4)[i] = 0.f;
    __syncthreads();
    float bin[7][4];
    #pragma unroll
    for (int u = 0; u < 7; ++u)
        #pragma unroll
        for (int r2 = 0; r2 < 4; ++r2) bin[u][r2] = 0.f;
    #pragma unroll
    for (int i = 0; i < 4; ++i)
        #pragma unroll
        for (int j = 0; j < 4; ++j)
            #pragma unroll
            for (int r2 = 0; r2 < 4; ++r2) bin[i - j + 3][r2] += acc[i][j][r2];
    const int basei = (wr - wc) * 64 + g * 4 - m + 127;
    #pragma unroll
    for (int u = 0; u < 7; ++u)
        #pragma unroll
        for (int r2 = 0; r2 < 4; ++r2)
            atomicAdd(&sd4[w][basei + (u - 3) * 16 + r2], bin[u][r2]);
    __syncthreads();
    const int doff = (mt - nt) * 128 + 511 - 127;
    if (tid < 255) {
        const float vsum = sd4[0][tid] + sd4[1][tid] + sd4[2][tid] + sd4[3][tid];
        atomicAdd(&S[b * 1023 + doff + tid], vsum);
    }
}

// ---------------------------------------------------------------------------
// Kernel P: P̄[b][f] = sum_j S[b][j] e^{-2πi f (j-511)/1024}.
// One wave per (b,f): lanes split j, exact sincosf per term, butterfly reduce.
// ---------------------------------------------------------------------------
__global__ __launch_bounds__(64) void k_pdft(const float* __restrict__ S,
                                             float* __restrict__ pbar) {
    const int b = blockIdx.y;
    const int f = blockIdx.x;              // 0..512
    const int lane = threadIdx.x;
    const float w = 2.0f * 3.14159265358979323846f / 1024.0f;
    float re = 0.f, im = 0.f;
    #pragma unroll
    for (int i = 0; i < 16; ++i) {
        const int j = lane + 64 * i;
        if (j < 1023) {
            const int mm = (f * (j - 511)) & 1023;   // exact mod (pow2, two's compl.)
            float s, c;
            sincosf(w * (float)mm, &s, &c);
            const float x = S[b * 1023 + j];
            re = fmaf(x, c, re);
            im = fmaf(x, -s, im);
        }
    }
    #pragma unroll
    for (int off = 32; off; off >>= 1) {
        re += __shfl_xor(re, off);
        im += __shfl_xor(im, off);
    }
    if (lane == 0) {
        pbar[b * 2 * NF + 2 * f]     = re;
        pbar[b * 2 * NF + 2 * f + 1] = im;
    }
}

// ---------------------------------------------------------------------------
// Kernel B: mean_value[b,t] = (1/(2047*1024)) * (P̄[0] + 2Σ_{f=1..512}
//            (P̄re[f] cos(2πft/2047) - P̄im[f] sin(2πft/2047)))
// One wave per (b,t), 4 waves/block; lanes split f, butterfly reduce.
// ---------------------------------------------------------------------------
__global__ __launch_bounds__(256) void k_mean(const float* __restrict__ pbar,
                                              float* __restrict__ mv) {
    __shared__ float P[2 * NF];
    const int b = blockIdx.y;
    for (int i = threadIdx.x; i < 2 * NF; i += 256)
        P[i] = pbar[(size_t)b * (2 * NF) + i];
    __syncthreads();
    const int wave = threadIdx.x >> 6, lane = threadIdx.x & 63;
    const int t = blockIdx.x * 4 + wave;   // 0..2047
    if (t >= NT) return;
    const float w2 = 2.0f * 3.14159265358979323846f / 2047.0f;
    float acc = 0.f;
    #pragma unroll
    for (int i = 0; i < 8; ++i) {
        const int f = 1 + lane + 64 * i;   // covers 1..512 exactly
        const int mm = (f * t) % 2047;
        float s, c;
        sincosf(w2 * (float)mm, &s, &c);
        acc = fmaf(P[2 * f], c, acc);
        acc = fmaf(-P[2 * f + 1], s, acc);
    }
    acc *= 2.0f;
    #pragma unroll
    for (int off = 32; off; off >>= 1) acc += __shfl_xor(acc, off);
    if (lane == 0)
        mv[(size_t)b * NT + t] = (acc + P[0]) * (1.0f / (2047.0f * 1024.0f));
}

// ---------------------------------------------------------------------------
// Kernel C: per-batch exact top-20 (ties -> lower index), softmax; batch 0's
// indices -> shifts. 256 threads: 8-iter scans + wave/LDS reduce.
// ---------------------------------------------------------------------------
__global__ __launch_bounds__(256) void k_topk(const float* __restrict__ mv,
                                              float* __restrict__ wts,
                                              int* __restrict__ shifts) {
    __shared__ float v[NT];
    __shared__ float topv[TOPK];
    __shared__ int   topi[TOPK];
    __shared__ float wv[4];
    __shared__ int   wi[4];
    const int b = blockIdx.x;
    const int t = threadIdx.x;
    const int lane = t & 63, wave = t >> 6;
    for (int i = t; i < NT; i += 256) v[i] = mv[(size_t)b * NT + i];
    __syncthreads();
    for (int kkk = 0; kkk < TOPK; ++kkk) {
        float bv = -INFINITY; int bi = 0x7fffffff;
        #pragma unroll
        for (int s = 0; s < 8; ++s) {
            const int i = t + 256 * s;
            if (i < NT) {
                const float x = v[i];
                if (x > bv) { bv = x; bi = i; }
            }
        }
        #pragma unroll
        for (int off = 32; off; off >>= 1) {
            const float ov = __shfl_down(bv, off);
            const int   oi = __shfl_down(bi, off);
            if (ov > bv || (ov == bv && oi < bi)) { bv = ov; bi = oi; }
        }
        if (lane == 0) { wv[wave] = bv; wi[wave] = bi; }
        __syncthreads();
        if (t == 0) {
            bv = wv[0]; bi = wi[0];
            #pragma unroll
            for (int ww = 1; ww < 4; ++ww)
                if (wv[ww] > bv || (wv[ww] == bv && wi[ww] < bi)) { bv = wv[ww]; bi = wi[ww]; }
            topv[kkk] = bv; topi[kkk] = bi;
            v[bi] = -INFINITY;
        }
        __syncthreads();
    }
    if (t == 0) {
        float m = topv[0], sum = 0.f, e[TOPK];
        #pragma unroll
        for (int i = 0; i < TOPK; ++i) { e[i] = expf(topv[i] - m); sum += e[i]; }
        #pragma unroll
        for (int i = 0; i < TOPK; ++i) wts[b * TOPK + i] = e[i] / sum;
        if (b == 0) {
            #pragma unroll
            for (int i = 0; i < TOPK; ++i) shifts[i] = topi[i];
        }
    }
}

// ---------------------------------------------------------------------------
// Kernel D: out[b,l,:] = Σ_k w[b,k] * values[b, (l+shift_k) & 1023, :]
// b = blockIdx.x & 7: XCD affinity so values[b] (2.1 MB) stays L2-resident.
// ---------------------------------------------------------------------------
__global__ __launch_bounds__(128) void k_out(const float* __restrict__ vals,
                                             const float* __restrict__ wts,
                                             const int* __restrict__ shifts,
                                             float* __restrict__ out) {
    __shared__ float w[TOPK];
    __shared__ int   sh[TOPK];
    const int id = blockIdx.x;
    const int b = id & 7;                // XCD affinity
    const int l = id >> 3;
    const int t = threadIdx.x;
    if (t < TOPK) { w[t] = wts[b * TOPK + t]; sh[t] = shifts[t]; }
    __syncthreads();
    float4 acc = make_float4(0.f, 0.f, 0.f, 0.f);
    const float4* vb = (const float4*)(vals + (size_t)b * NL * ND);
    #pragma unroll 4
    for (int kkk = 0; kkk < TOPK; ++kkk) {
        const int sl = (l + sh[kkk]) & (NL - 1);
        const float4 x = vb[(size_t)sl * (ND / 4) + t];
        const float wk = w[kkk];
        acc.x = fmaf(wk, x.x, acc.x);
        acc.y = fmaf(wk, x.y, acc.y);
        acc.z = fmaf(wk, x.z, acc.z);
        acc.w = fmaf(wk, x.w, acc.w);
    }
    ((float4*)out)[((size_t)b * NL + l) * (ND / 4) + t] = acc;
}

extern "C" void kernel_launch(void* const* d_in, const int* in_sizes, int n_in,
                              void* d_out, int out_size, void* d_ws, size_t ws_size,
                              hipStream_t stream) {
    const float* q = (const float*)d_in[0];
    const float* k = (const float*)d_in[1];
    const float* v = (const float*)d_in[2];
    float* out    = (float*)d_out;

    const size_t plane = (size_t)ND * NL;                 // 512*1024
    unsigned short* Thi = (unsigned short*)d_ws;          // 2*NB planes bf16
    unsigned short* Tlo = Thi + 2 * NB * plane;           // 2*NB planes bf16
    float* S      = (float*)(Tlo + 2 * NB * plane);       // NB * 1023
    float* pbar   = S + NB * 1023;                        // NB * 2*NF
    float* mv     = pbar + NB * 2 * NF;                   // NB * NT
    float* wts    = mv + NB * NT;                         // NB * TOPK
    int*   shifts = (int*)(wts + NB * TOPK);              // TOPK ints

    hipMemsetAsync(S, 0, NB * 1023 * sizeof(float), stream);
    k_tr  <<<dim3(128, NB, 2), 256, 0, stream>>>(q, k, Thi, Tlo);
    k_gemm<<<512, 256, 0, stream>>>(Thi, Tlo, S);
    k_pdft<<<dim3(NF, NB), 64, 0, stream>>>(S, pbar);
    k_mean<<<dim3(512, NB), 256, 0, stream>>>(pbar, mv);
    k_topk<<<NB, 256, 0, stream>>>(mv, wts, shifts);
    k_out <<<NL * NB, 128, 0, stream>>>(v, wts, shifts, out);
}